// Round 5
// baseline (128.288 us; speedup 1.0000x reference)
//
#include <hip/hip_runtime.h>
#include <math.h>

#define BATCH 8
#define NPRI  4096
#define TOPK  200

typedef unsigned long long u64;
typedef unsigned int u32;

#define WS_SOA (BATCH * NPRI)  // floats per SoA array
// workspace: [0, 6*WS_SOA*4) = SoA x1,y1,x2,y2,area,score (sorted order)
//            [KEY_OFF, +256KB) = u64 sort keys per original index
#define KEY_OFF ((size_t)6 * WS_SOA * sizeof(float))

// correctly-rounded f32 exp via f64 (matches numpy float32 exp bit-exactly)
__device__ __forceinline__ float exp_f32_cr(float x) { return (float)exp((double)x); }

// ---------------------------------------------------------------------------
// K0: softmax scores -> sort keys. key = (~score_bits)<<32 | idx  (ascending
// key order == descending score, ties -> ascending index == stable argsort(-s))
// ---------------------------------------------------------------------------
__global__ __launch_bounds__(256) void key_kernel(const float* __restrict__ conf,
                                                  u64* __restrict__ kbuf) {
  const int g = blockIdx.x * 256 + threadIdx.x;  // 0..32767
  const float2 c = ((const float2*)conf)[g];
  float m  = fmaxf(c.x, c.y);
  float e0 = exp_f32_cr(__fsub_rn(c.x, m));
  float e1 = exp_f32_cr(__fsub_rn(c.y, m));
  float s  = __fdiv_rn(e1, __fadd_rn(e0, e1));
  kbuf[g] = ((u64)(~__float_as_uint(s)) << 32) | (u32)(g & (NPRI - 1));
}

// ---------------------------------------------------------------------------
// K1: counting-rank sort + decode + scatter. 256 blocks x 256 thr.
// Block covers 128 original indices of one image; each index is ranked by two
// threads (j-halves 0..2047 / 2048..4095) with wave-uniform j (scalar loads),
// partials combined in LDS. Owning thread decodes its box (coalesced loc/prior
// reads) and scatters the SoA row to position `rank`.
// ---------------------------------------------------------------------------
__global__ __launch_bounds__(256) void rank_decode_kernel(
    const float* __restrict__ loc, const float* __restrict__ prior,
    const u64* __restrict__ kbuf, float* __restrict__ ws) {
  __shared__ u32 prank[2][128];
  const int blk = blockIdx.x;
  const int b = blk >> 5;            // 32 blocks per image
  const int tile = blk & 31;         // 128-wide i-tile
  const int t = threadIdx.x;
  const int half = t >> 7;           // wave-uniform (waves 0,1 vs 2,3)
  const int il = tile * 128 + (t & 127);  // original index within image

  const u64* kb = kbuf + b * NPRI;
  const u64 myk = kb[il];

  // wave-uniform j base -> scalar/broadcast loads
  const int jbase = __builtin_amdgcn_readfirstlane(half * 2048);
  const u64* p = kb + jbase;
  u32 c0 = 0, c1 = 0, c2 = 0, c3 = 0;
#pragma unroll 4
  for (int j = 0; j < 2048; j += 4) {
    c0 += (p[j + 0] < myk);
    c1 += (p[j + 1] < myk);
    c2 += (p[j + 2] < myk);
    c3 += (p[j + 3] < myk);
  }
  prank[half][t & 127] = (c0 + c1) + (c2 + c3);
  __syncthreads();

  if (half == 0) {
    const int rank = (int)(prank[0][t & 127] + prank[1][t & 127]);
    const float s = __uint_as_float(~(u32)(myk >> 32));
    const float4 l = ((const float4*)loc)[b * NPRI + il];
    const float4 pq = ((const float4*)prior)[il];
    float cx = __fadd_rn(pq.x, __fmul_rn(__fmul_rn(l.x, 0.1f), pq.z));
    float cy = __fadd_rn(pq.y, __fmul_rn(__fmul_rn(l.y, 0.1f), pq.w));
    float w  = __fmul_rn(pq.z, exp_f32_cr(__fmul_rn(l.z, 0.2f)));
    float h  = __fmul_rn(pq.w, exp_f32_cr(__fmul_rn(l.w, 0.2f)));
    float hw = __fmul_rn(w, 0.5f), hh = __fmul_rn(h, 0.5f);
    float x1 = __fsub_rn(cx, hw), x2 = __fadd_rn(cx, hw);
    float y1 = __fsub_rn(cy, hh), y2 = __fadd_rn(cy, hh);
    const int o = b * NPRI + rank;
    float* sx1 = ws;
    float* sy1 = ws + 1 * WS_SOA;
    float* sx2 = ws + 2 * WS_SOA;
    float* sy2 = ws + 3 * WS_SOA;
    float* sar = ws + 4 * WS_SOA;
    float* ssc = ws + 5 * WS_SOA;
    sx1[o] = x1; sy1[o] = y1; sx2[o] = x2; sy2[o] = y2;
    sar[o] = __fmul_rn(__fsub_rn(x2, x1), __fsub_rn(y2, y1));
    ssc[o] = s;
  }
}

// ---------------------------------------------------------------------------
// K2: lazy-mask greedy NMS (unchanged from Round 4 — verified bit-exact).
// One block (4 waves) per image; per chunk: kept-list suppression (4-way wave
// split + ballot), 64x64 diagonal via ballots, wave-0 serial resolve.
// ---------------------------------------------------------------------------
__global__ __launch_bounds__(256) void nms_scan_kernel(const float* __restrict__ ws,
                                                       float* __restrict__ out) {
  __shared__ float4 kbox[TOPK];
  __shared__ float  karea[TOPK];
  __shared__ float4 bx[64];
  __shared__ float  ba[64];
  __shared__ u64 diag[64];
  __shared__ u64 parts[4];
  __shared__ int klist[TOPK];
  __shared__ int s_kcnt, s_cnt, s_stop, s_total;

  const int b = blockIdx.x, t = threadIdx.x, lane = t & 63, wv = t >> 6;
  const float* sx1 = ws;
  const float* sy1 = ws + 1 * WS_SOA;
  const float* sx2 = ws + 2 * WS_SOA;
  const float* sy2 = ws + 3 * WS_SOA;
  const float* sar = ws + 4 * WS_SOA;
  const float* ssc = ws + 5 * WS_SOA;
  // exact threshold: fl(inter/uni) > 0.45f  <=>  inter > M*uni (exact in f64)
  const double M = 0.5 * ((double)0.45f + (double)__uint_as_float(0x3EE66667u));

  if (t == 0) { s_kcnt = 0; s_cnt = 0; s_stop = 0; s_total = 0; }
  __syncthreads();

  for (int c = 0; c < 64; ++c) {
    const int col = c * 64 + lane, o = b * NPRI + col;
    const float x1 = sx1[o], y1 = sy1[o], x2 = sx2[o], y2 = sy2[o], ar = sar[o];
    const int kcnt = s_kcnt;  // stable since previous chunk's final barrier
    if (wv == 0) { bx[lane] = make_float4(x1, y1, x2, y2); ba[lane] = ar; }
    __syncthreads();

    // phase 1: suppression of my column by previously-kept boxes
    bool supp = false;
    for (int k = wv; k < kcnt; k += 4) {
      float4 kb = kbox[k]; float ka = karea[k];
      float iw = fmaxf(__fsub_rn(fminf(kb.z, x2), fmaxf(kb.x, x1)), 0.0f);
      float ih = fmaxf(__fsub_rn(fminf(kb.w, y2), fmaxf(kb.y, y1)), 0.0f);
      float inter = __fmul_rn(iw, ih);
      float uni   = __fsub_rn(__fadd_rn(ka, ar), inter);
      if ((double)inter > M * (double)uni) { supp = true; break; }
    }
    u64 bw = __ballot(supp);
    if (lane == 0) parts[wv] = bw;

    // phase 2: diagonal rows 16wv..16wv+15 (row r vs all 64 cols of chunk)
#pragma unroll 4
    for (int r = 16 * wv; r < 16 * wv + 16; ++r) {
      float4 rb = bx[r]; float ra = ba[r];
      float iw = fmaxf(__fsub_rn(fminf(rb.z, x2), fmaxf(rb.x, x1)), 0.0f);
      float ih = fmaxf(__fsub_rn(fminf(rb.w, y2), fmaxf(rb.y, y1)), 0.0f);
      float inter = __fmul_rn(iw, ih);
      float uni   = __fsub_rn(__fadd_rn(ra, ar), inter);
      u64 dw = __ballot((double)inter > M * (double)uni);
      if (lane == 0) diag[r] = dw;
    }
    __syncthreads();

    // phase 3: serial resolve (wave 0)
    if (wv == 0) {
      float sc = ssc[o];
      u64 vm = __ballot(sc > 0.01f);
      int cnt = s_cnt;
      bool stop = false;
      if (vm == 0) {
        stop = true;  // sorted desc: nothing valid beyond here
      } else {
        u64 rw = parts[0] | parts[1] | parts[2] | parts[3];
        u64 ck = 0;
        for (int g = 0; g < 64; g += 8) {
          u64 d[8];
#pragma unroll
          for (int q = 0; q < 8; ++q) d[q] = diag[g + q];
#pragma unroll
          for (int q = 0; q < 8; ++q) {
            u64 kbit = ((vm & ~rw) >> (g + q)) & 1ull;
            rw |= d[q] & (0ull - kbit);
            ck |= kbit << (g + q);
          }
        }
        if ((ck >> lane) & 1ull) {
          int pos = cnt + __popcll(ck & ((1ull << lane) - 1ull));
          if (pos < TOPK) {
            klist[pos] = col;
            kbox[pos] = make_float4(x1, y1, x2, y2);
            karea[pos] = ar;
          }
        }
        cnt += __popcll(ck);
        if (cnt >= TOPK) stop = true;
      }
      if (lane == 0) {
        int capped = cnt < TOPK ? cnt : TOPK;
        s_kcnt = capped; s_cnt = cnt; s_total = capped; s_stop = stop ? 1 : 0;
      }
    }
    __syncthreads();
    if (s_stop) break;
  }

  const int total = s_total;
  for (int p = t; p < total; p += 256) {
    int i = klist[p];
    int o = b * NPRI + i;
    float* dst = out + (((size_t)b * 2 + 1) * TOPK + p) * 5;
    dst[0] = ssc[o]; dst[1] = sx1[o]; dst[2] = sy1[o]; dst[3] = sx2[o]; dst[4] = sy2[o];
  }
}

// ---------------------------------------------------------------------------
extern "C" void kernel_launch(void* const* d_in, const int* in_sizes, int n_in,
                              void* d_out, int out_size, void* d_ws, size_t ws_size,
                              hipStream_t stream) {
  const float* loc   = (const float*)d_in[0];
  const float* conf  = (const float*)d_in[1];
  const float* prior = (const float*)d_in[2];
  float* out = (float*)d_out;
  float* ws  = (float*)d_ws;
  u64*   kbuf = (u64*)((char*)d_ws + KEY_OFF);

  hipMemsetAsync(d_out, 0, (size_t)out_size * sizeof(float), stream);
  key_kernel<<<(BATCH * NPRI) / 256, 256, 0, stream>>>(conf, kbuf);
  rank_decode_kernel<<<256, 256, 0, stream>>>(loc, prior, kbuf, ws);
  nms_scan_kernel<<<BATCH, 256, 0, stream>>>(ws, out);
}

// Round 6
// 116.779 us; speedup vs baseline: 1.0986x; 1.0986x over previous
//
#include <hip/hip_runtime.h>
#include <math.h>

#define BATCH 8
#define NPRI  4096
#define TOPK  200

typedef unsigned long long u64;
typedef unsigned int u32;

#define WS_SOA (BATCH * NPRI)  // floats per SoA array
// workspace: [0, 6*WS_SOA*4) = SoA x1,y1,x2,y2,area,score (sorted order)
//            [KEY_OFF, +256KB) = u64 sort keys per original index
#define KEY_OFF ((size_t)6 * WS_SOA * sizeof(float))

// correctly-rounded f32 exp via f64 (matches numpy float32 exp bit-exactly)
__device__ __forceinline__ float exp_f32_cr(float x) { return (float)exp((double)x); }

// ---------------------------------------------------------------------------
// K0: softmax scores -> sort keys. key = (~score_bits)<<32 | idx  (ascending
// key order == descending score, ties -> ascending index == stable argsort(-s))
// ---------------------------------------------------------------------------
__global__ __launch_bounds__(256) void key_kernel(const float* __restrict__ conf,
                                                  u64* __restrict__ kbuf) {
  const int g = blockIdx.x * 256 + threadIdx.x;  // 0..32767
  const float2 c = ((const float2*)conf)[g];
  float m  = fmaxf(c.x, c.y);
  float e0 = exp_f32_cr(__fsub_rn(c.x, m));
  float e1 = exp_f32_cr(__fsub_rn(c.y, m));
  float s  = __fdiv_rn(e1, __fadd_rn(e0, e1));
  kbuf[g] = ((u64)(~__float_as_uint(s)) << 32) | (u32)(g & (NPRI - 1));
}

// ---------------------------------------------------------------------------
// K1: counting-rank sort + decode + scatter, LDS-staged.
// 256 blocks (32/image), 256 thr. Block stages all 4096 image keys in LDS
// (coalesced ulonglong2 loads; 32KB). Thread t ranks i = tile*128 + (t&127)
// over j-half (t>>7): wave-uniform j -> ds_read_b128 broadcast, 2 keys/read.
// Halves combined in LDS; threads t<128 decode (coalesced loc/prior float4)
// and scatter the SoA row to position rank.
// ---------------------------------------------------------------------------
__global__ __launch_bounds__(256) void rank_decode_kernel(
    const float* __restrict__ loc, const float* __restrict__ prior,
    const u64* __restrict__ kbuf, float* __restrict__ ws) {
  __shared__ u64 sk[NPRI];        // 32 KB: this image's keys
  __shared__ u32 prank[2][128];
  const int blk = blockIdx.x;
  const int b = blk >> 5;         // 32 blocks per image
  const int tile = blk & 31;      // 128-wide i-tile
  const int t = threadIdx.x;
  const int il = t & 127;         // i within tile
  const int jh = t >> 7;          // j-half; wave-uniform (waves 0,1 vs 2,3)

  // stage keys: 4096 u64 = 2048 ulonglong2, coalesced
  {
    const ulonglong2* kb2 = (const ulonglong2*)(kbuf + b * NPRI);
    ulonglong2* sk2 = (ulonglong2*)sk;
    for (int k = t; k < NPRI / 2; k += 256) sk2[k] = kb2[k];
  }
  __syncthreads();

  const u64 myk = sk[tile * 128 + il];

  // rank partial over my j-half, 8 keys per unrolled group (4 b128 reads)
  u32 cnt = 0;
  {
    const ulonglong2* sk2 = (const ulonglong2*)sk;
    const int j0 = jh * 1024;  // in ulonglong2 units (2048 keys per half)
#pragma unroll 4
    for (int j = j0; j < j0 + 1024; ++j) {
      ulonglong2 kk = sk2[j];
      cnt += (kk.x < myk);
      cnt += (kk.y < myk);
    }
  }
  prank[jh][il] = cnt;
  __syncthreads();

  if (t < 128) {
    const int rank = (int)(prank[0][t] + prank[1][t]);
    const int ig = tile * 128 + t;  // original index within image
    const float s = __uint_as_float(~(u32)(myk >> 32));
    const float4 l = ((const float4*)loc)[b * NPRI + ig];
    const float4 pq = ((const float4*)prior)[ig];
    float cx = __fadd_rn(pq.x, __fmul_rn(__fmul_rn(l.x, 0.1f), pq.z));
    float cy = __fadd_rn(pq.y, __fmul_rn(__fmul_rn(l.y, 0.1f), pq.w));
    float w  = __fmul_rn(pq.z, exp_f32_cr(__fmul_rn(l.z, 0.2f)));
    float h  = __fmul_rn(pq.w, exp_f32_cr(__fmul_rn(l.w, 0.2f)));
    float hw = __fmul_rn(w, 0.5f), hh = __fmul_rn(h, 0.5f);
    float x1 = __fsub_rn(cx, hw), x2 = __fadd_rn(cx, hw);
    float y1 = __fsub_rn(cy, hh), y2 = __fadd_rn(cy, hh);
    const int o = b * NPRI + rank;
    float* sx1 = ws;
    float* sy1 = ws + 1 * WS_SOA;
    float* sx2 = ws + 2 * WS_SOA;
    float* sy2 = ws + 3 * WS_SOA;
    float* sar = ws + 4 * WS_SOA;
    float* ssc = ws + 5 * WS_SOA;
    sx1[o] = x1; sy1[o] = y1; sx2[o] = x2; sy2[o] = y2;
    sar[o] = __fmul_rn(__fsub_rn(x2, x1), __fsub_rn(y2, y1));
    ssc[o] = s;
  }
}

// ---------------------------------------------------------------------------
// K2: lazy-mask greedy NMS (verified logic). One block (4 waves) per image.
// Now also zeroes its image's full output slice (replaces host-side memset).
// ---------------------------------------------------------------------------
__global__ __launch_bounds__(256) void nms_scan_kernel(const float* __restrict__ ws,
                                                       float* __restrict__ out) {
  __shared__ float4 kbox[TOPK];
  __shared__ float  karea[TOPK];
  __shared__ float4 bx[64];
  __shared__ float  ba[64];
  __shared__ u64 diag[64];
  __shared__ u64 parts[4];
  __shared__ int klist[TOPK];
  __shared__ int s_kcnt, s_cnt, s_stop, s_total;

  const int b = blockIdx.x, t = threadIdx.x, lane = t & 63, wv = t >> 6;
  const float* sx1 = ws;
  const float* sy1 = ws + 1 * WS_SOA;
  const float* sx2 = ws + 2 * WS_SOA;
  const float* sy2 = ws + 3 * WS_SOA;
  const float* sar = ws + 4 * WS_SOA;
  const float* ssc = ws + 5 * WS_SOA;
  // exact threshold: fl(inter/uni) > 0.45f  <=>  inter > M*uni (exact in f64)
  const double M = 0.5 * ((double)0.45f + (double)__uint_as_float(0x3EE66667u));

  // zero this image's output slice (harness poisons d_out before every call)
  float* slice = out + (size_t)b * 2 * TOPK * 5;
  for (int p = t; p < 2 * TOPK * 5; p += 256) slice[p] = 0.0f;

  if (t == 0) { s_kcnt = 0; s_cnt = 0; s_stop = 0; s_total = 0; }
  __syncthreads();

  for (int c = 0; c < 64; ++c) {
    const int col = c * 64 + lane, o = b * NPRI + col;
    const float x1 = sx1[o], y1 = sy1[o], x2 = sx2[o], y2 = sy2[o], ar = sar[o];
    const int kcnt = s_kcnt;  // stable since previous chunk's final barrier
    if (wv == 0) { bx[lane] = make_float4(x1, y1, x2, y2); ba[lane] = ar; }
    __syncthreads();

    // phase 1: suppression of my column by previously-kept boxes
    bool supp = false;
    for (int k = wv; k < kcnt; k += 4) {
      float4 kb = kbox[k]; float ka = karea[k];
      float iw = fmaxf(__fsub_rn(fminf(kb.z, x2), fmaxf(kb.x, x1)), 0.0f);
      float ih = fmaxf(__fsub_rn(fminf(kb.w, y2), fmaxf(kb.y, y1)), 0.0f);
      float inter = __fmul_rn(iw, ih);
      float uni   = __fsub_rn(__fadd_rn(ka, ar), inter);
      if ((double)inter > M * (double)uni) { supp = true; break; }
    }
    u64 bw = __ballot(supp);
    if (lane == 0) parts[wv] = bw;

    // phase 2: diagonal rows 16wv..16wv+15 (row r vs all 64 cols of chunk)
#pragma unroll 4
    for (int r = 16 * wv; r < 16 * wv + 16; ++r) {
      float4 rb = bx[r]; float ra = ba[r];
      float iw = fmaxf(__fsub_rn(fminf(rb.z, x2), fmaxf(rb.x, x1)), 0.0f);
      float ih = fmaxf(__fsub_rn(fminf(rb.w, y2), fmaxf(rb.y, y1)), 0.0f);
      float inter = __fmul_rn(iw, ih);
      float uni   = __fsub_rn(__fadd_rn(ra, ar), inter);
      u64 dw = __ballot((double)inter > M * (double)uni);
      if (lane == 0) diag[r] = dw;
    }
    __syncthreads();

    // phase 3: serial resolve (wave 0)
    if (wv == 0) {
      float sc = ssc[o];
      u64 vm = __ballot(sc > 0.01f);
      int cnt = s_cnt;
      bool stop = false;
      if (vm == 0) {
        stop = true;  // sorted desc: nothing valid beyond here
      } else {
        u64 rw = parts[0] | parts[1] | parts[2] | parts[3];
        u64 ck = 0;
        for (int g = 0; g < 64; g += 8) {
          u64 d[8];
#pragma unroll
          for (int q = 0; q < 8; ++q) d[q] = diag[g + q];
#pragma unroll
          for (int q = 0; q < 8; ++q) {
            u64 kbit = ((vm & ~rw) >> (g + q)) & 1ull;
            rw |= d[q] & (0ull - kbit);
            ck |= kbit << (g + q);
          }
        }
        if ((ck >> lane) & 1ull) {
          int pos = cnt + __popcll(ck & ((1ull << lane) - 1ull));
          if (pos < TOPK) {
            klist[pos] = col;
            kbox[pos] = make_float4(x1, y1, x2, y2);
            karea[pos] = ar;
          }
        }
        cnt += __popcll(ck);
        if (cnt >= TOPK) stop = true;
      }
      if (lane == 0) {
        int capped = cnt < TOPK ? cnt : TOPK;
        s_kcnt = capped; s_cnt = cnt; s_total = capped; s_stop = stop ? 1 : 0;
      }
    }
    __syncthreads();
    if (s_stop) break;
  }

  const int total = s_total;
  for (int p = t; p < total; p += 256) {
    int i = klist[p];
    int o = b * NPRI + i;
    float* dst = out + (((size_t)b * 2 + 1) * TOPK + p) * 5;
    dst[0] = ssc[o]; dst[1] = sx1[o]; dst[2] = sy1[o]; dst[3] = sx2[o]; dst[4] = sy2[o];
  }
}

// ---------------------------------------------------------------------------
extern "C" void kernel_launch(void* const* d_in, const int* in_sizes, int n_in,
                              void* d_out, int out_size, void* d_ws, size_t ws_size,
                              hipStream_t stream) {
  const float* loc   = (const float*)d_in[0];
  const float* conf  = (const float*)d_in[1];
  const float* prior = (const float*)d_in[2];
  float* out = (float*)d_out;
  float* ws  = (float*)d_ws;
  u64*   kbuf = (u64*)((char*)d_ws + KEY_OFF);

  key_kernel<<<(BATCH * NPRI) / 256, 256, 0, stream>>>(conf, kbuf);
  rank_decode_kernel<<<256, 256, 0, stream>>>(loc, prior, kbuf, ws);
  nms_scan_kernel<<<BATCH, 256, 0, stream>>>(ws, out);
}

// Round 7
// 104.619 us; speedup vs baseline: 1.2262x; 1.1162x over previous
//
#include <hip/hip_runtime.h>
#include <math.h>

#define BATCH 8
#define NPRI  4096
#define TOPK  200

typedef unsigned long long u64;
typedef unsigned int u32;

#define WS_SOA (BATCH * NPRI)  // floats per SoA array

// correctly-rounded f32 exp via f64 (matches numpy float32 exp bit-exactly)
__device__ __forceinline__ float exp_f32_cr(float x) { return (float)exp((double)x); }

// ---------------------------------------------------------------------------
// K1: fused key + counting-rank sort + decode + scatter.
// 256 blocks (32/image), 256 thr. Block computes ALL 4096 softmax keys of its
// image into LDS (redundant x32, ~1us), then ranks its 128-i tile:
//   thread t: owns i-pair (t&63) of the tile, streams j-quarter (t>>6, one per
//   wave -> wave-uniform ds_read_b128 broadcast), G=2 keys per read -> 256
//   pairs/instr. Partials combined in LDS; t<128 decodes + scatters to rank.
// ---------------------------------------------------------------------------
__global__ __launch_bounds__(256) void rank_decode_kernel(
    const float* __restrict__ loc, const float* __restrict__ conf,
    const float* __restrict__ prior, float* __restrict__ ws) {
  __shared__ u64 sk[NPRI];        // 32 KB: this image's keys
  __shared__ u32 prank[4][128];   // 2 KB: per-quarter partial ranks
  const int blk = blockIdx.x;
  const int b = blk >> 5;         // 32 blocks per image
  const int tile = blk & 31;      // 128-wide i-tile
  const int t = threadIdx.x;
  const int iq = t & 63;          // i-pair index within tile
  const int wv = t >> 6;          // wave id == j-quarter (wave-uniform)

  // ---- keys: softmax -> (~score_bits)<<32 | idx  (stable argsort(-s)) ----
  {
    const float2* cf = (const float2*)conf + b * NPRI;
#pragma unroll 4
    for (int g = t; g < NPRI; g += 256) {
      float2 c = cf[g];
      float m  = fmaxf(c.x, c.y);
      float e0 = exp_f32_cr(__fsub_rn(c.x, m));
      float e1 = exp_f32_cr(__fsub_rn(c.y, m));
      float s  = __fdiv_rn(e1, __fadd_rn(e0, e1));
      sk[g] = ((u64)(~__float_as_uint(s)) << 32) | (u32)g;
    }
  }
  __syncthreads();

  // ---- rank: G=2 i-keys vs wave-uniform j-quarter stream ----
  const ulonglong2* sk2 = (const ulonglong2*)sk;
  const ulonglong2 mypair = sk2[tile * 64 + iq];
  const u64 myk0 = mypair.x, myk1 = mypair.y;
  u32 cnt0 = 0, cnt1 = 0;
  {
    const int r0 = wv * 512;  // 512 ulonglong2 = 1024 keys per quarter
#pragma unroll 4
    for (int r = r0; r < r0 + 512; ++r) {
      ulonglong2 kk = sk2[r];
      cnt0 += (kk.x < myk0); cnt0 += (kk.y < myk0);
      cnt1 += (kk.x < myk1); cnt1 += (kk.y < myk1);
    }
  }
  prank[wv][iq * 2 + 0] = cnt0;
  prank[wv][iq * 2 + 1] = cnt1;
  __syncthreads();

  // ---- decode + scatter (threads 0..127, coalesced loc/prior reads) ----
  if (t < 128) {
    const int rank = (int)(prank[0][t] + prank[1][t] + prank[2][t] + prank[3][t]);
    const int ig = tile * 128 + t;  // original index within image
    const u64 myk = sk[ig];
    const float s = __uint_as_float(~(u32)(myk >> 32));
    const float4 l = ((const float4*)loc)[b * NPRI + ig];
    const float4 pq = ((const float4*)prior)[ig];
    float cx = __fadd_rn(pq.x, __fmul_rn(__fmul_rn(l.x, 0.1f), pq.z));
    float cy = __fadd_rn(pq.y, __fmul_rn(__fmul_rn(l.y, 0.1f), pq.w));
    float w  = __fmul_rn(pq.z, exp_f32_cr(__fmul_rn(l.z, 0.2f)));
    float h  = __fmul_rn(pq.w, exp_f32_cr(__fmul_rn(l.w, 0.2f)));
    float hw = __fmul_rn(w, 0.5f), hh = __fmul_rn(h, 0.5f);
    float x1 = __fsub_rn(cx, hw), x2 = __fadd_rn(cx, hw);
    float y1 = __fsub_rn(cy, hh), y2 = __fadd_rn(cy, hh);
    const int o = b * NPRI + rank;
    float* sx1 = ws;
    float* sy1 = ws + 1 * WS_SOA;
    float* sx2 = ws + 2 * WS_SOA;
    float* sy2 = ws + 3 * WS_SOA;
    float* sar = ws + 4 * WS_SOA;
    float* ssc = ws + 5 * WS_SOA;
    sx1[o] = x1; sy1[o] = y1; sx2[o] = x2; sy2[o] = y2;
    sar[o] = __fmul_rn(__fsub_rn(x2, x1), __fsub_rn(y2, y1));
    ssc[o] = s;
  }
}

// ---------------------------------------------------------------------------
// K2: lazy-mask greedy NMS (verified logic) + software-pipelined chunk loads.
// One block (4 waves) per image; zeroes its own output slice.
// ---------------------------------------------------------------------------
__global__ __launch_bounds__(256) void nms_scan_kernel(const float* __restrict__ ws,
                                                       float* __restrict__ out) {
  __shared__ float4 kbox[TOPK];
  __shared__ float  karea[TOPK];
  __shared__ float4 bx[64];
  __shared__ float  ba[64];
  __shared__ u64 diag[64];
  __shared__ u64 parts[4];
  __shared__ int klist[TOPK];
  __shared__ int s_kcnt, s_cnt, s_stop, s_total;

  const int b = blockIdx.x, t = threadIdx.x, lane = t & 63, wv = t >> 6;
  const float* sx1 = ws;
  const float* sy1 = ws + 1 * WS_SOA;
  const float* sx2 = ws + 2 * WS_SOA;
  const float* sy2 = ws + 3 * WS_SOA;
  const float* sar = ws + 4 * WS_SOA;
  const float* ssc = ws + 5 * WS_SOA;
  // exact threshold: fl(inter/uni) > 0.45f  <=>  inter > M*uni (exact in f64)
  const double M = 0.5 * ((double)0.45f + (double)__uint_as_float(0x3EE66667u));

  // zero this image's output slice (harness poisons d_out before every call)
  float* slice = out + (size_t)b * 2 * TOPK * 5;
  for (int p = t; p < 2 * TOPK * 5; p += 256) slice[p] = 0.0f;

  if (t == 0) { s_kcnt = 0; s_cnt = 0; s_stop = 0; s_total = 0; }

  // prefetch chunk 0
  int o_n = b * NPRI + lane;
  float nx1 = sx1[o_n], ny1 = sy1[o_n], nx2 = sx2[o_n], ny2 = sy2[o_n];
  float nar = sar[o_n], nsc = ssc[o_n];
  __syncthreads();

  for (int c = 0; c < 64; ++c) {
    const int col = c * 64 + lane, o = b * NPRI + col;
    const float x1 = nx1, y1 = ny1, x2 = nx2, y2 = ny2, ar = nar, sc = nsc;
    // issue next chunk's loads early (in flight during phases 1-3)
    if (c + 1 < 64) {
      const int on = o + 64;
      nx1 = sx1[on]; ny1 = sy1[on]; nx2 = sx2[on]; ny2 = sy2[on];
      nar = sar[on]; nsc = ssc[on];
    }
    const int kcnt = s_kcnt;  // stable since previous chunk's final barrier
    if (wv == 0) { bx[lane] = make_float4(x1, y1, x2, y2); ba[lane] = ar; }
    __syncthreads();

    // phase 1: suppression of my column by previously-kept boxes
    bool supp = false;
    for (int k = wv; k < kcnt; k += 4) {
      float4 kb = kbox[k]; float ka = karea[k];
      float iw = fmaxf(__fsub_rn(fminf(kb.z, x2), fmaxf(kb.x, x1)), 0.0f);
      float ih = fmaxf(__fsub_rn(fminf(kb.w, y2), fmaxf(kb.y, y1)), 0.0f);
      float inter = __fmul_rn(iw, ih);
      float uni   = __fsub_rn(__fadd_rn(ka, ar), inter);
      if ((double)inter > M * (double)uni) { supp = true; break; }
    }
    u64 bw = __ballot(supp);
    if (lane == 0) parts[wv] = bw;

    // phase 2: diagonal rows 16wv..16wv+15 (row r vs all 64 cols of chunk)
#pragma unroll 4
    for (int r = 16 * wv; r < 16 * wv + 16; ++r) {
      float4 rb = bx[r]; float ra = ba[r];
      float iw = fmaxf(__fsub_rn(fminf(rb.z, x2), fmaxf(rb.x, x1)), 0.0f);
      float ih = fmaxf(__fsub_rn(fminf(rb.w, y2), fmaxf(rb.y, y1)), 0.0f);
      float inter = __fmul_rn(iw, ih);
      float uni   = __fsub_rn(__fadd_rn(ra, ar), inter);
      u64 dw = __ballot((double)inter > M * (double)uni);
      if (lane == 0) diag[r] = dw;
    }
    __syncthreads();

    // phase 3: serial resolve (wave 0)
    if (wv == 0) {
      u64 vm = __ballot(sc > 0.01f);
      int cnt = s_cnt;
      bool stop = false;
      if (vm == 0) {
        stop = true;  // sorted desc: nothing valid beyond here
      } else {
        u64 rw = parts[0] | parts[1] | parts[2] | parts[3];
        u64 ck = 0;
        for (int g = 0; g < 64; g += 8) {
          u64 d[8];
#pragma unroll
          for (int q = 0; q < 8; ++q) d[q] = diag[g + q];
#pragma unroll
          for (int q = 0; q < 8; ++q) {
            u64 kbit = ((vm & ~rw) >> (g + q)) & 1ull;
            rw |= d[q] & (0ull - kbit);
            ck |= kbit << (g + q);
          }
        }
        if ((ck >> lane) & 1ull) {
          int pos = cnt + __popcll(ck & ((1ull << lane) - 1ull));
          if (pos < TOPK) {
            klist[pos] = col;
            kbox[pos] = make_float4(x1, y1, x2, y2);
            karea[pos] = ar;
          }
        }
        cnt += __popcll(ck);
        if (cnt >= TOPK) stop = true;
      }
      if (lane == 0) {
        int capped = cnt < TOPK ? cnt : TOPK;
        s_kcnt = capped; s_cnt = cnt; s_total = capped; s_stop = stop ? 1 : 0;
      }
    }
    __syncthreads();
    if (s_stop) break;
  }

  const int total = s_total;
  for (int p = t; p < total; p += 256) {
    int i = klist[p];
    int o = b * NPRI + i;
    float* dst = out + (((size_t)b * 2 + 1) * TOPK + p) * 5;
    dst[0] = ssc[o]; dst[1] = sx1[o]; dst[2] = sy1[o]; dst[3] = sx2[o]; dst[4] = sy2[o];
  }
}

// ---------------------------------------------------------------------------
extern "C" void kernel_launch(void* const* d_in, const int* in_sizes, int n_in,
                              void* d_out, int out_size, void* d_ws, size_t ws_size,
                              hipStream_t stream) {
  const float* loc   = (const float*)d_in[0];
  const float* conf  = (const float*)d_in[1];
  const float* prior = (const float*)d_in[2];
  float* out = (float*)d_out;
  float* ws  = (float*)d_ws;

  rank_decode_kernel<<<256, 256, 0, stream>>>(loc, conf, prior, ws);
  nms_scan_kernel<<<BATCH, 256, 0, stream>>>(ws, out);
}

// Round 8
// 90.010 us; speedup vs baseline: 1.4253x; 1.1623x over previous
//
#include <hip/hip_runtime.h>
#include <math.h>

#define BATCH 8
#define NPRI  4096
#define TOPK  200

typedef unsigned long long u64;
typedef unsigned int u32;

#define WS_SOA (BATCH * NPRI)  // floats per SoA array

// correctly-rounded f32 exp via f64 (matches numpy float32 exp bit-exactly)
__device__ __forceinline__ float exp_f32_cr(float x) { return (float)exp((double)x); }

// ---------------------------------------------------------------------------
// K1: fused key + counting-rank sort + decode + scatter.
// 256 blocks (32/image), 256 thr. Block computes ALL 4096 softmax keys of its
// image into LDS, then ranks its 128-i tile with G=4 register i-keys:
//   thread t: owns i-quad (t&31)*4, streams j-range (t>>5) of 8 (512 keys).
//   Half-wave j split -> 2 distinct LDS addresses per b128 read (2-way: free).
//   1024 ds_read_b128/CU (~5us) vs 134M u64-compares VALU floor (~4us).
// ---------------------------------------------------------------------------
__global__ __launch_bounds__(256) void rank_decode_kernel(
    const float* __restrict__ loc, const float* __restrict__ conf,
    const float* __restrict__ prior, float* __restrict__ ws) {
  __shared__ u64 sk[NPRI];        // 32 KB: this image's keys
  __shared__ u32 prank[8][128];   // 4 KB: per-range partial ranks
  const int blk = blockIdx.x;
  const int b = blk >> 5;         // 32 blocks per image
  const int tile = blk & 31;      // 128-wide i-tile
  const int t = threadIdx.x;
  const int ig = t & 31;          // i-quad index (i = tile*128 + ig*4 + 0..3)
  const int rg = t >> 5;          // j-range 0..7 (512 keys each); half-wave uniform

  // ---- keys: softmax -> (~score_bits)<<32 | idx  (stable argsort(-s)) ----
  {
    const float2* cf = (const float2*)conf + b * NPRI;
#pragma unroll 4
    for (int g = t; g < NPRI; g += 256) {
      float2 c = cf[g];
      float m  = fmaxf(c.x, c.y);
      float e0 = exp_f32_cr(__fsub_rn(c.x, m));
      float e1 = exp_f32_cr(__fsub_rn(c.y, m));
      float s  = __fdiv_rn(e1, __fadd_rn(e0, e1));
      sk[g] = ((u64)(~__float_as_uint(s)) << 32) | (u32)g;
    }
  }
  __syncthreads();

  // ---- rank: G=4 i-keys vs j-range stream ----
  const ulonglong2* sk2 = (const ulonglong2*)sk;
  const ulonglong2 pA = sk2[tile * 64 + ig * 2];
  const ulonglong2 pB = sk2[tile * 64 + ig * 2 + 1];
  const u64 k0 = pA.x, k1 = pA.y, k2 = pB.x, k3 = pB.y;
  u32 c0 = 0, c1 = 0, c2 = 0, c3 = 0;
  {
    const int r0 = rg * 256;  // 256 ulonglong2 = 512 keys per range
#pragma unroll 4
    for (int r = r0; r < r0 + 256; ++r) {
      ulonglong2 kk = sk2[r];
      c0 += (kk.x < k0); c0 += (kk.y < k0);
      c1 += (kk.x < k1); c1 += (kk.y < k1);
      c2 += (kk.x < k2); c2 += (kk.y < k2);
      c3 += (kk.x < k3); c3 += (kk.y < k3);
    }
  }
  ((uint4*)prank[rg])[ig] = make_uint4(c0, c1, c2, c3);
  __syncthreads();

  // ---- decode + scatter (threads 0..127, coalesced loc/prior reads) ----
  if (t < 128) {
    int rank = 0;
#pragma unroll
    for (int q = 0; q < 8; ++q) rank += (int)prank[q][t];
    const int ig2 = tile * 128 + t;  // original index within image
    const u64 myk = sk[ig2];
    const float s = __uint_as_float(~(u32)(myk >> 32));
    const float4 l = ((const float4*)loc)[b * NPRI + ig2];
    const float4 pq = ((const float4*)prior)[ig2];
    float cx = __fadd_rn(pq.x, __fmul_rn(__fmul_rn(l.x, 0.1f), pq.z));
    float cy = __fadd_rn(pq.y, __fmul_rn(__fmul_rn(l.y, 0.1f), pq.w));
    float w  = __fmul_rn(pq.z, exp_f32_cr(__fmul_rn(l.z, 0.2f)));
    float h  = __fmul_rn(pq.w, exp_f32_cr(__fmul_rn(l.w, 0.2f)));
    float hw = __fmul_rn(w, 0.5f), hh = __fmul_rn(h, 0.5f);
    float x1 = __fsub_rn(cx, hw), x2 = __fadd_rn(cx, hw);
    float y1 = __fsub_rn(cy, hh), y2 = __fadd_rn(cy, hh);
    const int o = b * NPRI + rank;
    float* sx1 = ws;
    float* sy1 = ws + 1 * WS_SOA;
    float* sx2 = ws + 2 * WS_SOA;
    float* sy2 = ws + 3 * WS_SOA;
    float* sar = ws + 4 * WS_SOA;
    float* ssc = ws + 5 * WS_SOA;
    sx1[o] = x1; sy1[o] = y1; sx2[o] = x2; sy2[o] = y2;
    sar[o] = __fmul_rn(__fsub_rn(x2, x1), __fsub_rn(y2, y1));
    ssc[o] = s;
  }
}

// ---------------------------------------------------------------------------
// K2: lazy-mask greedy NMS (verified logic), 8 waves/block for phases 1-2.
// One block per image; zeroes its own output slice; register-prefetched
// chunk loads.
// ---------------------------------------------------------------------------
__global__ __launch_bounds__(512) void nms_scan_kernel(const float* __restrict__ ws,
                                                       float* __restrict__ out) {
  __shared__ float4 kbox[TOPK];
  __shared__ float  karea[TOPK];
  __shared__ float4 bx[64];
  __shared__ float  ba[64];
  __shared__ u64 diag[64];
  __shared__ u64 parts[8];
  __shared__ int klist[TOPK];
  __shared__ int s_kcnt, s_cnt, s_stop, s_total;

  const int b = blockIdx.x, t = threadIdx.x, lane = t & 63, wv = t >> 6;
  const float* sx1 = ws;
  const float* sy1 = ws + 1 * WS_SOA;
  const float* sx2 = ws + 2 * WS_SOA;
  const float* sy2 = ws + 3 * WS_SOA;
  const float* sar = ws + 4 * WS_SOA;
  const float* ssc = ws + 5 * WS_SOA;
  // exact threshold: fl(inter/uni) > 0.45f  <=>  inter > M*uni (exact in f64)
  const double M = 0.5 * ((double)0.45f + (double)__uint_as_float(0x3EE66667u));

  // zero this image's output slice (harness poisons d_out before every call)
  float* slice = out + (size_t)b * 2 * TOPK * 5;
  for (int p = t; p < 2 * TOPK * 5; p += 512) slice[p] = 0.0f;

  if (t == 0) { s_kcnt = 0; s_cnt = 0; s_stop = 0; s_total = 0; }

  // prefetch chunk 0 (every thread keeps its own copy; L1-served redundancy)
  int o_n = b * NPRI + lane;
  float nx1 = sx1[o_n], ny1 = sy1[o_n], nx2 = sx2[o_n], ny2 = sy2[o_n];
  float nar = sar[o_n], nsc = ssc[o_n];
  __syncthreads();

  for (int c = 0; c < 64; ++c) {
    const int col = c * 64 + lane, o = b * NPRI + col;
    const float x1 = nx1, y1 = ny1, x2 = nx2, y2 = ny2, ar = nar, sc = nsc;
    // issue next chunk's loads early (in flight during phases 1-3)
    if (c + 1 < 64) {
      const int on = o + 64;
      nx1 = sx1[on]; ny1 = sy1[on]; nx2 = sx2[on]; ny2 = sy2[on];
      nar = sar[on]; nsc = ssc[on];
    }
    const int kcnt = s_kcnt;  // stable since previous chunk's final barrier
    if (wv == 0) { bx[lane] = make_float4(x1, y1, x2, y2); ba[lane] = ar; }
    __syncthreads();

    // phase 1: suppression of my column by previously-kept boxes (8-way split)
    bool supp = false;
    for (int k = wv; k < kcnt; k += 8) {
      float4 kb = kbox[k]; float ka = karea[k];
      float iw = fmaxf(__fsub_rn(fminf(kb.z, x2), fmaxf(kb.x, x1)), 0.0f);
      float ih = fmaxf(__fsub_rn(fminf(kb.w, y2), fmaxf(kb.y, y1)), 0.0f);
      float inter = __fmul_rn(iw, ih);
      float uni   = __fsub_rn(__fadd_rn(ka, ar), inter);
      if ((double)inter > M * (double)uni) { supp = true; break; }
    }
    u64 bw = __ballot(supp);
    if (lane == 0) parts[wv] = bw;

    // phase 2: diagonal rows 8wv..8wv+7 (row r vs all 64 cols of chunk)
#pragma unroll
    for (int r = 8 * wv; r < 8 * wv + 8; ++r) {
      float4 rb = bx[r]; float ra = ba[r];
      float iw = fmaxf(__fsub_rn(fminf(rb.z, x2), fmaxf(rb.x, x1)), 0.0f);
      float ih = fmaxf(__fsub_rn(fminf(rb.w, y2), fmaxf(rb.y, y1)), 0.0f);
      float inter = __fmul_rn(iw, ih);
      float uni   = __fsub_rn(__fadd_rn(ra, ar), inter);
      u64 dw = __ballot((double)inter > M * (double)uni);
      if (lane == 0) diag[r] = dw;
    }
    __syncthreads();

    // phase 3: serial resolve (wave 0)
    if (wv == 0) {
      u64 vm = __ballot(sc > 0.01f);
      int cnt = s_cnt;
      bool stop = false;
      if (vm == 0) {
        stop = true;  // sorted desc: nothing valid beyond here
      } else {
        u64 rw = parts[0] | parts[1] | parts[2] | parts[3] |
                 parts[4] | parts[5] | parts[6] | parts[7];
        u64 ck = 0;
        for (int g = 0; g < 64; g += 8) {
          u64 d[8];
#pragma unroll
          for (int q = 0; q < 8; ++q) d[q] = diag[g + q];
#pragma unroll
          for (int q = 0; q < 8; ++q) {
            u64 kbit = ((vm & ~rw) >> (g + q)) & 1ull;
            rw |= d[q] & (0ull - kbit);
            ck |= kbit << (g + q);
          }
        }
        if ((ck >> lane) & 1ull) {
          int pos = cnt + __popcll(ck & ((1ull << lane) - 1ull));
          if (pos < TOPK) {
            klist[pos] = col;
            kbox[pos] = make_float4(x1, y1, x2, y2);
            karea[pos] = ar;
          }
        }
        cnt += __popcll(ck);
        if (cnt >= TOPK) stop = true;
      }
      if (lane == 0) {
        int capped = cnt < TOPK ? cnt : TOPK;
        s_kcnt = capped; s_cnt = cnt; s_total = capped; s_stop = stop ? 1 : 0;
      }
    }
    __syncthreads();
    if (s_stop) break;
  }

  const int total = s_total;
  for (int p = t; p < total; p += 512) {
    int i = klist[p];
    int o = b * NPRI + i;
    float* dst = out + (((size_t)b * 2 + 1) * TOPK + p) * 5;
    dst[0] = ssc[o]; dst[1] = sx1[o]; dst[2] = sy1[o]; dst[3] = sx2[o]; dst[4] = sy2[o];
  }
}

// ---------------------------------------------------------------------------
extern "C" void kernel_launch(void* const* d_in, const int* in_sizes, int n_in,
                              void* d_out, int out_size, void* d_ws, size_t ws_size,
                              hipStream_t stream) {
  const float* loc   = (const float*)d_in[0];
  const float* conf  = (const float*)d_in[1];
  const float* prior = (const float*)d_in[2];
  float* out = (float*)d_out;
  float* ws  = (float*)d_ws;

  rank_decode_kernel<<<256, 256, 0, stream>>>(loc, conf, prior, ws);
  nms_scan_kernel<<<BATCH, 512, 0, stream>>>(ws, out);
}